// Round 3
// baseline (356.178 us; speedup 1.0000x reference)
//
#include <hip/hip_runtime.h>

typedef short v8s __attribute__((ext_vector_type(8)));
typedef float v4f __attribute__((ext_vector_type(4)));
typedef float f32x16 __attribute__((ext_vector_type(16)));
typedef unsigned int v2u __attribute__((ext_vector_type(2)));
typedef unsigned int v4u __attribute__((ext_vector_type(4)));

#define NC 256
#define ND 128

__device__ __forceinline__ unsigned short f2bf(float f) {
  union { float f; unsigned int u; } v; v.f = f;
  unsigned int u = v.u;
  unsigned int r = (u + 0x7fffu + ((u >> 16) & 1u)) >> 16;
  return (unsigned short)r;
}

__device__ __forceinline__ unsigned int cvt_pk_bf16(float a, float b) {
  unsigned int r;
  asm("v_cvt_pk_bf16_f32 %0, %1, %2" : "=v"(r) : "v"(a), "v"(b));
  return r;
}

__device__ __forceinline__ float bf_lo(unsigned int u) { return __uint_as_float(u << 16); }
__device__ __forceinline__ float bf_hi(unsigned int u) { return __uint_as_float(u & 0xffff0000u); }

// ---------------- prep: fragment-arranged bf16 P/G/PT, norms, gate ----------------
__global__ void som_prep_kernel(const float* __restrict__ P, const float* __restrict__ G,
                                const float* __restrict__ gate_logits,
                                unsigned short* __restrict__ PbfA, unsigned short* __restrict__ GbfA,
                                unsigned short* __restrict__ PTbfA,
                                float* __restrict__ b2p, float* __restrict__ b2g,
                                float* __restrict__ gatev) {
  int c = blockIdx.x;      // 0..255
  int t = threadIdx.x;     // 0..127 (= d / k index)
  float p = P[c * ND + t];
  float g = G[c * ND + t];

  int ct = c >> 5, l31 = c & 31;
  int s = t >> 4, hia = (t >> 3) & 1, j = t & 7;
  int lane = l31 + 32 * hia;
  PbfA[((ct * 8 + s) * 64 + lane) * 8 + j] = f2bf(p);
  GbfA[((ct * 8 + s) * 64 + lane) * 8 + j] = f2bf(g);

  int dt = t >> 5, l31d = t & 31;
  int sc = c >> 4, hic = (c >> 3) & 1, jc = c & 7;
  int laned = l31d + 32 * hic;
  PTbfA[((dt * 16 + sc) * 64 + laned) * 8 + jc] = f2bf(p);

  float pp = p * p, gg = g * g;
  #pragma unroll
  for (int m = 1; m < 64; m <<= 1) { pp += __shfl_xor(pp, m); gg += __shfl_xor(gg, m); }
  __shared__ float sp[2], sg[2];
  if ((t & 63) == 0) { sp[t >> 6] = pp; sg[t >> 6] = gg; }
  __syncthreads();
  if (t == 0) {
    b2p[c] = sp[0] + sp[1];
    b2g[c] = sg[0] + sg[1];
    gatev[c] = 1.f / (1.f + expf(-gate_logits[c]));
  }
}

// ---------------- kernel 1: distances + softmax stats, u -> w_out stash ----------------
// 1 wave = 32 rows. u (= e*gate, bf16) for row m stored at w_out row m, cols 128..255
// (bytes m*1024+512 .. +1024). scale stored at blended_out[m*128].
__global__ __launch_bounds__(256, 4) void som_dist_kernel(
    const float* __restrict__ x,
    const unsigned short* __restrict__ PbfA,
    const unsigned short* __restrict__ GbfA,
    const float* __restrict__ b2p,
    const float* __restrict__ b2g,
    const float* __restrict__ gatev,
    const float* __restrict__ temp_raw,
    float* __restrict__ blended_out,
    float* __restrict__ w_out)
{
  const int tid  = threadIdx.x;
  const int wid  = tid >> 6;
  const int lane = tid & 63;
  const int l31  = lane & 31;
  const int hi   = lane >> 5;
  const long long R = ((long long)blockIdx.x * 4 + wid) * 32;

  float traw = temp_raw[0];
  float sgm = 1.f / (1.f + __builtin_amdgcn_exp2f(-traw * 1.44269504f));
  float T = sgm * (1.f - 1e-3f) + 1e-3f;
  float k2 = 1.44269504f / T;                 // e = exp2(-d * k2)

  // ---- X B-fragments (col m = l31, k-chunk hi*8) + exact f32 row norm ----
  const float* xr = x + (R + l31) * ND + hi * 8;
  v8s xb[8];
  float a2 = 0.f;
  #pragma unroll
  for (int s = 0; s < 8; ++s) {
    v4f lo  = *(const v4f*)(xr + s * 16);
    v4f hi4 = *(const v4f*)(xr + s * 16 + 4);
    v4u w;
    w[0] = cvt_pk_bf16(lo[0], lo[1]);
    w[1] = cvt_pk_bf16(lo[2], lo[3]);
    w[2] = cvt_pk_bf16(hi4[0], hi4[1]);
    w[3] = cvt_pk_bf16(hi4[2], hi4[3]);
    xb[s] = __builtin_bit_cast(v8s, w);
    #pragma unroll
    for (int j = 0; j < 4; ++j) {
      a2 = fmaf(lo[j], lo[j], a2);
      a2 = fmaf(hi4[j], hi4[j], a2);
    }
  }
  a2 += __shfl_xor(a2, 32);

  unsigned int* urow = (unsigned int*)((char*)w_out + (size_t)(R + l31) * 1024 + 512);
  float s1 = 0.f, su = 0.f;
  const unsigned short* pb = PbfA + lane * 8;
  const unsigned short* gb = GbfA + lane * 8;
  #pragma unroll
  for (int ct = 0; ct < 8; ++ct) {
    f32x16 aP, aG;
    #pragma unroll
    for (int i = 0; i < 16; ++i) { aP[i] = 0.f; aG[i] = 0.f; }
    #pragma unroll
    for (int s = 0; s < 8; ++s) {
      v8s ap = *(const v8s*)(pb + (ct * 8 + s) * 512);
      v8s ag = *(const v8s*)(gb + (ct * 8 + s) * 512);
      aP = __builtin_amdgcn_mfma_f32_32x32x16_bf16(ap, xb[s], aP, 0, 0, 0);
      aG = __builtin_amdgcn_mfma_f32_32x32x16_bf16(ag, xb[s], aG, 0, 0, 0);
    }
    #pragma unroll
    for (int q = 0; q < 4; ++q) {
      int c0 = ct * 32 + q * 8 + hi * 4;
      v4f bp = *(const v4f*)(b2p + c0);
      v4f bg = *(const v4f*)(b2g + c0);
      v4f gt = *(const v4f*)(gatev + c0);
      float uf[4];
      #pragma unroll
      for (int j2 = 0; j2 < 4; ++j2) {
        int r = q * 4 + j2;
        float d2a = fmaf(-2.f, aP[r], a2 + bp[j2]);
        float d2b = fmaf(-2.f, aG[r], a2 + bg[j2]);
        float d = __builtin_amdgcn_sqrtf(fmaxf(d2a, 1e-12f))
                + __builtin_amdgcn_sqrtf(fmaxf(d2b, 1e-12f));
        float e = __builtin_amdgcn_exp2f(-d * k2);
        float uu = e * gt[j2];
        s1 += e; su += uu;
        uf[j2] = uu;
      }
      v2u pk;
      pk[0] = cvt_pk_bf16(uf[0], uf[1]);
      pk[1] = cvt_pk_bf16(uf[2], uf[3]);
      *(v2u*)(urow + ct * 16 + q * 4 + hi * 2) = pk;
    }
  }
  s1 += __shfl_xor(s1, 32);
  su += __shfl_xor(su, 32);
  // w = e*gate / (su + eps*(s1+eps))  — exact algebra of the double normalization
  float scale = 1.f / (su + 1e-8f * (s1 + 1e-8f));
  if (hi == 0) blended_out[(R + l31) * ND] = scale;
}

// ---------------- kernel 2: blend GEMM + w emit ----------------
// Reads u fragments (already in MFMA-B layout), emits w = u*scale (f32),
// blended^T = P^T(32d x 16c) * U^T(16c x 32m) * scale.
__global__ __launch_bounds__(256, 4) void som_blend_kernel(
    const unsigned short* __restrict__ PTbfA,
    float* __restrict__ blended_out,
    float* __restrict__ w_out)
{
  const int tid  = threadIdx.x;
  const int wid  = tid >> 6;
  const int lane = tid & 63;
  const int l31  = lane & 31;
  const int hi   = lane >> 5;
  const long long R = ((long long)blockIdx.x * 4 + wid) * 32;

  float scale = blended_out[(R + l31) * ND];                  // stashed by kernel 1
  const v4u* urow = (const v4u*)((char*)w_out + (size_t)(R + l31) * 1024 + 512);
  float* wrow = w_out + (size_t)(R + l31) * NC;

  f32x16 acc[4];
  #pragma unroll
  for (int dt = 0; dt < 4; ++dt)
    #pragma unroll
    for (int i = 0; i < 16; ++i) acc[dt][i] = 0.f;

  const unsigned short* tb = PTbfA + lane * 8;
  #pragma unroll
  for (int s2 = 0; s2 < 16; ++s2) {
    v4u bw = urow[s2 * 2 + hi];     // u[k = s2*16 + hi*8 .. +8][m = l31], bf16 pairs
    // emit w for these 8 columns (data-dependent on the load -> ordered before stores)
    v4f w0, w1;
    w0[0] = bf_lo(bw[0]) * scale; w0[1] = bf_hi(bw[0]) * scale;
    w0[2] = bf_lo(bw[1]) * scale; w0[3] = bf_hi(bw[1]) * scale;
    w1[0] = bf_lo(bw[2]) * scale; w1[1] = bf_hi(bw[2]) * scale;
    w1[2] = bf_lo(bw[3]) * scale; w1[3] = bf_hi(bw[3]) * scale;
    *(v4f*)(wrow + s2 * 16 + hi * 8)     = w0;
    *(v4f*)(wrow + s2 * 16 + hi * 8 + 4) = w1;

    v8s bfrag = __builtin_bit_cast(v8s, bw);
    #pragma unroll
    for (int dt = 0; dt < 4; ++dt) {
      v8s pa = *(const v8s*)(tb + (dt * 16 + s2) * 512);
      acc[dt] = __builtin_amdgcn_mfma_f32_32x32x16_bf16(pa, bfrag, acc[dt], 0, 0, 0);
    }
  }

  float* brow = blended_out + (size_t)(R + l31) * ND;
  #pragma unroll
  for (int dt = 0; dt < 4; ++dt) {
    #pragma unroll
    for (int q = 0; q < 4; ++q) {
      v4f ov;
      ov[0] = acc[dt][4 * q + 0] * scale;
      ov[1] = acc[dt][4 * q + 1] * scale;
      ov[2] = acc[dt][4 * q + 2] * scale;
      ov[3] = acc[dt][4 * q + 3] * scale;
      *(v4f*)(brow + dt * 32 + q * 8 + hi * 4) = ov;
    }
  }
}

extern "C" void kernel_launch(void* const* d_in, const int* in_sizes, int n_in,
                              void* d_out, int out_size, void* d_ws, size_t ws_size,
                              hipStream_t stream) {
  const float* x    = (const float*)d_in[0];
  const float* P    = (const float*)d_in[1];
  const float* G    = (const float*)d_in[2];
  const float* traw = (const float*)d_in[3];
  const float* gl   = (const float*)d_in[4];
  const int N = in_sizes[0] / ND;             // 262144

  char* ws = (char*)d_ws;
  unsigned short* PbfA  = (unsigned short*)(ws);
  unsigned short* GbfA  = (unsigned short*)(ws + 65536);
  unsigned short* PTbfA = (unsigned short*)(ws + 131072);
  float* b2p   = (float*)(ws + 196608);
  float* b2g   = (float*)(ws + 197632);
  float* gatev = (float*)(ws + 198656);

  float* blended = (float*)d_out;
  float* wout    = blended + (size_t)N * ND;

  som_prep_kernel<<<NC, ND, 0, stream>>>(P, G, gl, PbfA, GbfA, PTbfA, b2p, b2g, gatev);
  som_dist_kernel<<<N / 128, 256, 0, stream>>>(x, PbfA, GbfA, b2p, b2g, gatev,
                                               traw, blended, wout);
  som_blend_kernel<<<N / 128, 256, 0, stream>>>(PTbfA, blended, wout);
}

// Round 4
// 320.584 us; speedup vs baseline: 1.1110x; 1.1110x over previous
//
#include <hip/hip_runtime.h>

typedef short v8s __attribute__((ext_vector_type(8)));
typedef float v4f __attribute__((ext_vector_type(4)));
typedef float f32x16 __attribute__((ext_vector_type(16)));
typedef unsigned int v4u __attribute__((ext_vector_type(4)));

#define NC 256
#define ND 128

__device__ __forceinline__ unsigned short f2bf(float f) {
  union { float f; unsigned int u; } v; v.f = f;
  unsigned int u = v.u;
  unsigned int r = (u + 0x7fffu + ((u >> 16) & 1u)) >> 16;
  return (unsigned short)r;
}

__device__ __forceinline__ unsigned int cvt_pk_bf16(float a, float b) {
  unsigned int r;
  asm("v_cvt_pk_bf16_f32 %0, %1, %2" : "=v"(r) : "v"(a), "v"(b));
  return r;
}

__device__ __forceinline__ void plane32swap(unsigned int &a, unsigned int &b) {
  asm("v_permlane32_swap_b32 %0, %1" : "+v"(a), "+v"(b));
}

__device__ __forceinline__ float bf_lo(unsigned int u) { return __uint_as_float(u << 16); }
__device__ __forceinline__ float bf_hi(unsigned int u) { return __uint_as_float(u & 0xffff0000u); }

// ---------------- prep: fragment-arranged bf16 P/G/PT, norms, gate ----------------
__global__ void som_prep_kernel(const float* __restrict__ P, const float* __restrict__ G,
                                const float* __restrict__ gate_logits,
                                unsigned short* __restrict__ PbfA, unsigned short* __restrict__ GbfA,
                                unsigned short* __restrict__ PTbfA,
                                float* __restrict__ b2p, float* __restrict__ b2g,
                                float* __restrict__ gatev) {
  int c = blockIdx.x;      // 0..255
  int t = threadIdx.x;     // 0..127 (= d / k index)
  float p = P[c * ND + t];
  float g = G[c * ND + t];

  int ct = c >> 5, l31 = c & 31;
  int s = t >> 4, hia = (t >> 3) & 1, j = t & 7;
  int lane = l31 + 32 * hia;
  PbfA[((ct * 8 + s) * 64 + lane) * 8 + j] = f2bf(p);
  GbfA[((ct * 8 + s) * 64 + lane) * 8 + j] = f2bf(g);

  int dt = t >> 5, l31d = t & 31;
  int sc = c >> 4, hic = (c >> 3) & 1, jc = c & 7;
  int laned = l31d + 32 * hic;
  PTbfA[((dt * 16 + sc) * 64 + laned) * 8 + jc] = f2bf(p);

  float pp = p * p, gg = g * g;
  #pragma unroll
  for (int m = 1; m < 64; m <<= 1) { pp += __shfl_xor(pp, m); gg += __shfl_xor(gg, m); }
  __shared__ float sp[2], sg[2];
  if ((t & 63) == 0) { sp[t >> 6] = pp; sg[t >> 6] = gg; }
  __syncthreads();
  if (t == 0) {
    b2p[c] = sp[0] + sp[1];
    b2g[c] = sg[0] + sg[1];
    gatev[c] = 1.f / (1.f + expf(-gate_logits[c]));
  }
}

// ---------------- kernel 1: distances + stats; u -> B-frag stash (in blended region) ----
// Row-group g (32 rows) stash: bytes [g*16384, +16384) of blended region, layout
// [s2 0..15][lane 0..63][16B] — coalesced 1KB stores here, 1KB loads in kernel 2.
__global__ __launch_bounds__(256, 4) void som_dist_kernel(
    const float* __restrict__ x,
    const unsigned short* __restrict__ PbfA,
    const unsigned short* __restrict__ GbfA,
    const float* __restrict__ b2p,
    const float* __restrict__ b2g,
    const float* __restrict__ gatev,
    const float* __restrict__ temp_raw,
    float* __restrict__ stash_base,          // = blended region
    float* __restrict__ scalev)
{
  const int tid  = threadIdx.x;
  const int wid  = tid >> 6;
  const int lane = tid & 63;
  const int l31  = lane & 31;
  const int hi   = lane >> 5;
  const int g    = blockIdx.x * 4 + wid;
  const long long R = (long long)g * 32;

  float traw = temp_raw[0];
  float sgm = 1.f / (1.f + __builtin_amdgcn_exp2f(-traw * 1.44269504f));
  float T = sgm * (1.f - 1e-3f) + 1e-3f;
  float k2 = 1.44269504f / T;                 // e = exp2(-d * k2)

  // ---- X B-fragments (col m = l31, k-chunk hi*8) + exact f32 row norm ----
  const float* xr = x + (R + l31) * ND + hi * 8;
  v8s xb[8];
  float a2 = 0.f;
  #pragma unroll
  for (int s = 0; s < 8; ++s) {
    v4f lo  = *(const v4f*)(xr + s * 16);
    v4f hi4 = *(const v4f*)(xr + s * 16 + 4);
    v4u w;
    w[0] = cvt_pk_bf16(lo[0], lo[1]);
    w[1] = cvt_pk_bf16(lo[2], lo[3]);
    w[2] = cvt_pk_bf16(hi4[0], hi4[1]);
    w[3] = cvt_pk_bf16(hi4[2], hi4[3]);
    xb[s] = __builtin_bit_cast(v8s, w);
    #pragma unroll
    for (int j = 0; j < 4; ++j) {
      a2 = fmaf(lo[j], lo[j], a2);
      a2 = fmaf(hi4[j], hi4[j], a2);
    }
  }
  a2 += __shfl_xor(a2, 32);

  v4u* srow = (v4u*)((char*)stash_base + (size_t)g * 16384);
  float s1 = 0.f, su = 0.f;
  const unsigned short* pb = PbfA + lane * 8;
  const unsigned short* gb = GbfA + lane * 8;
  #pragma unroll
  for (int ct = 0; ct < 8; ++ct) {
    f32x16 aP, aG;
    #pragma unroll
    for (int i = 0; i < 16; ++i) { aP[i] = 0.f; aG[i] = 0.f; }
    #pragma unroll
    for (int s = 0; s < 8; ++s) {
      v8s ap = *(const v8s*)(pb + (ct * 8 + s) * 512);
      v8s ag = *(const v8s*)(gb + (ct * 8 + s) * 512);
      aP = __builtin_amdgcn_mfma_f32_32x32x16_bf16(ap, xb[s], aP, 0, 0, 0);
      aG = __builtin_amdgcn_mfma_f32_32x32x16_bf16(ag, xb[s], aG, 0, 0, 0);
    }
    unsigned int w8[8];
    #pragma unroll
    for (int q = 0; q < 4; ++q) {
      int c0 = ct * 32 + q * 8 + hi * 4;
      v4f bp = *(const v4f*)(b2p + c0);
      v4f bg = *(const v4f*)(b2g + c0);
      v4f gt = *(const v4f*)(gatev + c0);
      float uf[4];
      #pragma unroll
      for (int j2 = 0; j2 < 4; ++j2) {
        int r = q * 4 + j2;
        float d2a = fmaf(-2.f, aP[r], a2 + bp[j2]);
        float d2b = fmaf(-2.f, aG[r], a2 + bg[j2]);
        float d = __builtin_amdgcn_sqrtf(fmaxf(d2a, 1e-12f))
                + __builtin_amdgcn_sqrtf(fmaxf(d2b, 1e-12f));
        float e = __builtin_amdgcn_exp2f(-d * k2);
        float uu = e * gt[j2];
        s1 += e; su += uu;
        uf[j2] = uu;
      }
      w8[2 * q]     = cvt_pk_bf16(uf[0], uf[1]);
      w8[2 * q + 1] = cvt_pk_bf16(uf[2], uf[3]);
    }
    // convert C/D layout -> B-frag layout (verified R2 recipe), coalesced store
    #pragma unroll
    for (int b = 0; b < 2; ++b) {
      unsigned int p0 = w8[4 * b], p1 = w8[4 * b + 1], p2 = w8[4 * b + 2], p3 = w8[4 * b + 3];
      plane32swap(p0, p2);
      plane32swap(p1, p3);
      v4u bw; bw[0] = p0; bw[1] = p1; bw[2] = p2; bw[3] = p3;
      srow[(2 * ct + b) * 64 + lane] = bw;
    }
  }
  s1 += __shfl_xor(s1, 32);
  su += __shfl_xor(su, 32);
  // w = e*gate / (su + eps*(s1+eps))  — exact algebra of the double normalization
  float scale = 1.f / (su + 1e-8f * (s1 + 1e-8f));
  if (hi == 0) scalev[R + l31] = scale;
}

// ---------------- kernel 2: blend GEMM + w emit ----------------
// Reads coalesced B-frag stash (L3-hot), emits w (f32), accumulates
// blended^T = P^T(32d x 16c) * U^T(16c x 32m) * scale; final stores overwrite
// this wave's own stash bytes (safe: stores depend on all stash loads via acc).
__global__ __launch_bounds__(256, 4) void som_blend_kernel(
    const unsigned short* __restrict__ PTbfA,
    const float* __restrict__ scalev,
    float* __restrict__ blended_out,
    float* __restrict__ w_out)
{
  const int tid  = threadIdx.x;
  const int wid  = tid >> 6;
  const int lane = tid & 63;
  const int l31  = lane & 31;
  const int hi   = lane >> 5;
  const int g    = blockIdx.x * 4 + wid;
  const long long R = (long long)g * 32;

  float scale = scalev[R + l31];
  const v4u* srow = (const v4u*)((char*)blended_out + (size_t)g * 16384);
  float* wrow = w_out + (size_t)(R + l31) * NC + hi * 8;

  f32x16 acc[4];
  #pragma unroll
  for (int dt = 0; dt < 4; ++dt)
    #pragma unroll
    for (int i = 0; i < 16; ++i) acc[dt][i] = 0.f;

  const unsigned short* tb = PTbfA + lane * 8;
  #pragma unroll
  for (int s2 = 0; s2 < 16; ++s2) {
    v4u bw = srow[s2 * 64 + lane];              // coalesced 1KB wave load
    // w emit for c = s2*16 + hi*8 .. +8, row R+l31
    v4f w0, w1;
    w0[0] = bf_lo(bw[0]) * scale; w0[1] = bf_hi(bw[0]) * scale;
    w0[2] = bf_lo(bw[1]) * scale; w0[3] = bf_hi(bw[1]) * scale;
    w1[0] = bf_lo(bw[2]) * scale; w1[1] = bf_hi(bw[2]) * scale;
    w1[2] = bf_lo(bw[3]) * scale; w1[3] = bf_hi(bw[3]) * scale;
    *(v4f*)(wrow + s2 * 16)     = w0;
    *(v4f*)(wrow + s2 * 16 + 4) = w1;

    v8s bfrag = __builtin_bit_cast(v8s, bw);
    #pragma unroll
    for (int dt = 0; dt < 4; ++dt) {
      v8s pa = *(const v8s*)(tb + (dt * 16 + s2) * 512);
      acc[dt] = __builtin_amdgcn_mfma_f32_32x32x16_bf16(pa, bfrag, acc[dt], 0, 0, 0);
    }
  }

  float* brow = blended_out + (size_t)(R + l31) * ND + hi * 4;
  #pragma unroll
  for (int dt = 0; dt < 4; ++dt) {
    #pragma unroll
    for (int q = 0; q < 4; ++q) {
      v4f ov;
      ov[0] = acc[dt][4 * q + 0] * scale;
      ov[1] = acc[dt][4 * q + 1] * scale;
      ov[2] = acc[dt][4 * q + 2] * scale;
      ov[3] = acc[dt][4 * q + 3] * scale;
      *(v4f*)(brow + dt * 32 + q * 8) = ov;
    }
  }
}

extern "C" void kernel_launch(void* const* d_in, const int* in_sizes, int n_in,
                              void* d_out, int out_size, void* d_ws, size_t ws_size,
                              hipStream_t stream) {
  const float* x    = (const float*)d_in[0];
  const float* P    = (const float*)d_in[1];
  const float* G    = (const float*)d_in[2];
  const float* traw = (const float*)d_in[3];
  const float* gl   = (const float*)d_in[4];
  const int N = in_sizes[0] / ND;             // 262144

  char* ws = (char*)d_ws;
  unsigned short* PbfA  = (unsigned short*)(ws);
  unsigned short* GbfA  = (unsigned short*)(ws + 65536);
  unsigned short* PTbfA = (unsigned short*)(ws + 131072);
  float* b2p   = (float*)(ws + 196608);
  float* b2g   = (float*)(ws + 197632);
  float* gatev = (float*)(ws + 198656);
  float* scalev = (float*)(ws + 200704);      // N*4 bytes

  float* blended = (float*)d_out;
  float* wout    = blended + (size_t)N * ND;

  som_prep_kernel<<<NC, ND, 0, stream>>>(P, G, gl, PbfA, GbfA, PTbfA, b2p, b2g, gatev);
  som_dist_kernel<<<N / 128, 256, 0, stream>>>(x, PbfA, GbfA, b2p, b2g, gatev,
                                               traw, blended, scalev);
  som_blend_kernel<<<N / 128, 256, 0, stream>>>(PTbfA, scalev, blended, wout);
}